// Round 1
// baseline (192.235 us; speedup 1.0000x reference)
//
#include <hip/hip_runtime.h>
#include <cfloat>

// Problem constants (from reference): B=8, C=2, H=256, W=256
#define BB 8
#define CC 2
#define HH 256
#define WW 256

static constexpr float EDT_INF = 1e4f;          // matches reference INF
static constexpr int   NPIX    = BB * HH * WW;  // 524288

// ---------------------------------------------------------------------------
// K0a: init tmin slot
__global__ void k_tmin_init(int* tmin) { *tmin = 0x7fffffff; }

// K0b: global min of target (int), deterministic atomicMin
__global__ void k_tmin(const int* __restrict__ target, int n, int* __restrict__ tmin) {
    int local = 0x7fffffff;
    for (int idx = blockIdx.x * blockDim.x + threadIdx.x; idx < n;
         idx += gridDim.x * blockDim.x)
        local = min(local, target[idx]);
    __shared__ int s[256];
    s[threadIdx.x] = local;
    __syncthreads();
    for (int st = 128; st > 0; st >>= 1) {
        if (threadIdx.x < st) s[threadIdx.x] = min(s[threadIdx.x], s[threadIdx.x + st]);
        __syncthreads();
    }
    if (threadIdx.x == 0) atomicMin(tmin, s[0]);
}

// ---------------------------------------------------------------------------
// K1: vertical EDT scans. One thread per (b, w) column. Computes, for both
// sources (pc mask from argmax(preds), gt mask from target) and both
// polarities (m and !m), the squared vertical distance field:
//   fwd:  d = m ? carry+1 : 0   (carry init 1e4)    [top->down]
//   bwd:  same bottom->up;  g = min(fwd, bwd);  store g*g
// Exactly mirrors the reference float32 op sequence.
__global__ void k_vertical(const float* __restrict__ preds,
                           const int*   __restrict__ target,
                           const int*   __restrict__ tminp,
                           float* __restrict__ pc_m2,  float* __restrict__ pc_nm2,
                           float* __restrict__ gt_m2,  float* __restrict__ gt_nm2) {
    int t = blockIdx.x * blockDim.x + threadIdx.x;
    if (t >= BB * WW) return;
    int b = t / WW, w = t % WW;
    const float* p0 = preds + ((size_t)b * CC + 0) * HH * WW + w;
    const float* p1 = preds + ((size_t)b * CC + 1) * HH * WW + w;
    const int*   tg = target + (size_t)b * HH * WW + w;
    const int tmin = *tminp;
    const size_t base = (size_t)b * HH * WW + w;

    // mask bits for the 256 rows (avoids re-reading preds in the bwd pass)
    unsigned long long mpc[4] = {0, 0, 0, 0}, mgt[4] = {0, 0, 0, 0};

    float c_pm = EDT_INF, c_pn = EDT_INF, c_gm = EDT_INF, c_gn = EDT_INF;
    for (int i = 0; i < HH; ++i) {
        float a0 = p0[(size_t)i * WW];
        float a1 = p1[(size_t)i * WW];
        bool pc = (a1 > a0);                 // argmax over C=2, ties -> class 0
        int tv = tg[(size_t)i * WW];
        if (tv == 255) tv = tmin;
        bool gt = (tv > 0);                  // gt.astype(float) > 0

        mpc[i >> 6] |= ((unsigned long long)pc) << (i & 63);
        mgt[i >> 6] |= ((unsigned long long)gt) << (i & 63);

        c_pm = pc  ? c_pm + 1.0f : 0.0f;     // edt(pc>0): true pixels accumulate
        c_pn = !pc ? c_pn + 1.0f : 0.0f;     // edt(pc==0)
        c_gm = gt  ? c_gm + 1.0f : 0.0f;     // edt(gt>0)
        c_gn = !gt ? c_gn + 1.0f : 0.0f;     // edt(gt==0)

        size_t idx = base + (size_t)i * WW;
        pc_m2[idx]  = c_pm;   // temporarily store fwd value
        pc_nm2[idx] = c_pn;
        gt_m2[idx]  = c_gm;
        gt_nm2[idx] = c_gn;
    }

    c_pm = c_pn = c_gm = c_gn = EDT_INF;
    for (int i = HH - 1; i >= 0; --i) {
        bool pc = (mpc[i >> 6] >> (i & 63)) & 1ULL;
        bool gt = (mgt[i >> 6] >> (i & 63)) & 1ULL;
        c_pm = pc  ? c_pm + 1.0f : 0.0f;
        c_pn = !pc ? c_pn + 1.0f : 0.0f;
        c_gm = gt  ? c_gm + 1.0f : 0.0f;
        c_gn = !gt ? c_gn + 1.0f : 0.0f;

        size_t idx = base + (size_t)i * WW;
        float g;
        g = fminf(pc_m2[idx],  c_pm); pc_m2[idx]  = g * g;
        g = fminf(pc_nm2[idx], c_pn); pc_nm2[idx] = g * g;
        g = fminf(gt_m2[idx],  c_gm); gt_m2[idx]  = g * g;
        g = fminf(gt_nm2[idx], c_gn); gt_nm2[idx] = g * g;
    }
}

// ---------------------------------------------------------------------------
// K2: horizontal pass for pc. One block per (b,i) row; thread j computes
//   pc_dist = sqrt(min_k g2_sel[k] + (j-k)^2)
// where g2_sel is g2(m) for true pixels, g2(!m) for false pixels
// (edt(m)+edt(!m): the other term is exactly 0).
__global__ void k_horiz_pc(const float* __restrict__ preds,
                           const float* __restrict__ pc_m2,
                           const float* __restrict__ pc_nm2,
                           float* __restrict__ pc_dist) {
    const int row = blockIdx.x;              // 0 .. B*H-1
    const int b = row / HH, i = row % HH;
    const int j = threadIdx.x;
    const size_t base = (size_t)row * WW;

    __shared__ float sm[WW], snm[WW];
    sm[j]  = pc_m2[base + j];
    snm[j] = pc_nm2[base + j];
    __syncthreads();

    float a0 = preds[((size_t)b * CC + 0) * HH * WW + (size_t)i * WW + j];
    float a1 = preds[((size_t)b * CC + 1) * HH * WW + (size_t)i * WW + j];
    bool pc = (a1 > a0);
    const float* rowv = pc ? sm : snm;

    float mn = FLT_MAX;
#pragma unroll 8
    for (int k = 0; k < WW; ++k) {
        float fd = (float)(j - k);
        mn = fminf(mn, fd * fd + rowv[k]);
    }
    pc_dist[base + j] = sqrtf(mn);
}

// ---------------------------------------------------------------------------
// K3: horizontal pass for gt, fused with the final elementwise math and a
// per-block partial sum.
__global__ void k_horiz_gt_final(const float* __restrict__ preds,
                                 const int*   __restrict__ target,
                                 const int*   __restrict__ tminp,
                                 const float* __restrict__ gt_m2,
                                 const float* __restrict__ gt_nm2,
                                 const float* __restrict__ pc_dist,
                                 float* __restrict__ partials) {
    const int row = blockIdx.x;
    const int b = row / HH, i = row % HH;
    const int j = threadIdx.x;
    const size_t base = (size_t)row * WW;

    __shared__ float sm[WW], snm[WW];
    sm[j]  = gt_m2[base + j];
    snm[j] = gt_nm2[base + j];
    __syncthreads();

    int tv = target[base + j];
    if (tv == 255) tv = *tminp;
    float gtv = (float)tv;
    bool gt = (gtv > 0.0f);
    const float* rowv = gt ? sm : snm;

    float mn = FLT_MAX;
#pragma unroll 8
    for (int k = 0; k < WW; ++k) {
        float fd = (float)(j - k);
        mn = fminf(mn, fd * fd + rowv[k]);
    }
    float gd = sqrtf(mn);

    float a0 = preds[((size_t)b * CC + 0) * HH * WW + (size_t)i * WW + j];
    float a1 = preds[((size_t)b * CC + 1) * HH * WW + (size_t)i * WW + j];
    float pcv = (a1 > a0) ? 1.0f : 0.0f;

    float pd  = pc_dist[base + j];
    float err = fabsf(gtv - pcv);
    float dist = sqrtf(pd * pd + gd * gd);
    float mult = sqrtf(err * dist + 1e-9f);   // separate mul+add, like reference

    __shared__ float red[WW];
    red[j] = mult;
    __syncthreads();
    for (int st = 128; st > 0; st >>= 1) {
        if (j < st) red[j] += red[j + st];
        __syncthreads();
    }
    if (j == 0) partials[row] = red[0];
}

// ---------------------------------------------------------------------------
// K4: final deterministic reduction of B*H partials -> mean
__global__ void k_final(const float* __restrict__ partials, float* __restrict__ out) {
    __shared__ float s[256];
    float acc = 0.0f;
    for (int k = threadIdx.x; k < BB * HH; k += 256) acc += partials[k];
    s[threadIdx.x] = acc;
    __syncthreads();
    for (int st = 128; st > 0; st >>= 1) {
        if (threadIdx.x < st) s[threadIdx.x] += s[threadIdx.x + st];
        __syncthreads();
    }
    if (threadIdx.x == 0) out[0] = s[0] * (1.0f / (float)NPIX);  // /2^19: exact
}

// ---------------------------------------------------------------------------
extern "C" void kernel_launch(void* const* d_in, const int* in_sizes, int n_in,
                              void* d_out, int out_size, void* d_ws, size_t ws_size,
                              hipStream_t stream) {
    const float* preds  = (const float*)d_in[0];
    const int*   target = (const int*)d_in[1];
    float* out = (float*)d_out;

    const size_t N = (size_t)NPIX;
    float* ws      = (float*)d_ws;
    float* pc_m2   = ws;
    float* pc_nm2  = ws + 1 * N;
    float* gt_m2   = ws + 2 * N;
    float* gt_nm2  = ws + 3 * N;
    float* pc_dist = ws + 4 * N;
    float* partials = ws + 5 * N;              // B*H = 2048 floats
    int*   tmin    = (int*)(ws + 5 * N + 2048);

    k_tmin_init<<<1, 1, 0, stream>>>(tmin);
    k_tmin<<<256, 256, 0, stream>>>(target, NPIX, tmin);
    k_vertical<<<(BB * WW + 255) / 256, 256, 0, stream>>>(
        preds, target, tmin, pc_m2, pc_nm2, gt_m2, gt_nm2);
    k_horiz_pc<<<BB * HH, WW, 0, stream>>>(preds, pc_m2, pc_nm2, pc_dist);
    k_horiz_gt_final<<<BB * HH, WW, 0, stream>>>(
        preds, target, tmin, gt_m2, gt_nm2, pc_dist, partials);
    k_final<<<1, 256, 0, stream>>>(partials, out);
}

// Round 2
// 52.555 us; speedup vs baseline: 3.6578x; 3.6578x over previous
//
#include <hip/hip_runtime.h>
#include <cfloat>

// Problem constants (from reference): B=8, C=2, H=256, W=256
#define BB 8
#define CC 2
#define HH 256
#define WW 256

static constexpr float EDT_INF = 1e4f;          // matches reference INF
static constexpr int   NPIX    = BB * HH * WW;  // 524288

// ---------------------------------------------------------------------------
// K0a: init tmin slot
__global__ void k_tmin_init(int* tmin) { *tmin = 0x7fffffff; }

// K0b: global min of target (int), deterministic atomicMin
__global__ void k_tmin(const int* __restrict__ target, int n, int* __restrict__ tmin) {
    int local = 0x7fffffff;
    for (int idx = blockIdx.x * blockDim.x + threadIdx.x; idx < n;
         idx += gridDim.x * blockDim.x)
        local = min(local, target[idx]);
    __shared__ int s[256];
    s[threadIdx.x] = local;
    __syncthreads();
    for (int st = 128; st > 0; st >>= 1) {
        if (threadIdx.x < st) s[threadIdx.x] = min(s[threadIdx.x], s[threadIdx.x + st]);
        __syncthreads();
    }
    if (threadIdx.x == 0) atomicMin(tmin, s[0]);
}

// ---------------------------------------------------------------------------
// Closed-form vertical scan value from a 256-bit column mask.
// Reproduces exactly (in f32): fwd scan d = m ? carry+1 : 0, carry init 1e4,
// top->down; bwd bottom->up; g = min(fwd,bwd); returns g*g.
// All values are integer-valued floats (<= 1e4+256) -> exact.
__device__ __forceinline__ float g2_of(const unsigned long long* m, int i, bool set) {
    if (!set) return 0.0f;
    float fwd = EDT_INF + (float)(i + 1);     // run reaches top
    {
        int k = i - 1;
        if (k >= 0) {
            int w = k >> 6;
            unsigned long long t = ~m[w] & (~0ULL >> (63 - (k & 63)));
            for (;;) {
                if (t) { int j = (w << 6) + 63 - __builtin_clzll(t); fwd = (float)(i - j); break; }
                if (--w < 0) break;
                t = ~m[w];
            }
        }
    }
    float bwd = EDT_INF + (float)(HH - i);    // run reaches bottom
    {
        int k = i + 1;
        if (k < HH) {
            int w = k >> 6;
            unsigned long long t = ~m[w] & (~0ULL << (k & 63));
            for (;;) {
                if (t) { int j = (w << 6) + __builtin_ctzll(t); bwd = (float)(j - i); break; }
                if (++w >= 4) break;
                t = ~m[w];
            }
        }
    }
    float g = fminf(fwd, bwd);
    return g * g;
}

// ---------------------------------------------------------------------------
// K1: vertical EDT, one block per (b,w) column, one thread per row.
// Column masks built with one __ballot per wave; per-pixel closed form.
__global__ void k_vertical(const float* __restrict__ preds,
                           const int*   __restrict__ target,
                           const int*   __restrict__ tminp,
                           float* __restrict__ pc_m2,  float* __restrict__ pc_nm2,
                           float* __restrict__ gt_m2,  float* __restrict__ gt_nm2) {
    const int blk = blockIdx.x;            // b*W + w
    const int b = blk >> 8, w = blk & 255;
    const int i = threadIdx.x;             // row
    const int tmin = *tminp;

    const size_t img = (size_t)b * HH * WW;
    const size_t pix = img + (size_t)i * WW + w;

    float a0 = preds[((size_t)b * CC + 0) * HH * WW + (size_t)i * WW + w];
    float a1 = preds[((size_t)b * CC + 1) * HH * WW + (size_t)i * WW + w];
    bool pc = (a1 > a0);                   // argmax over C=2, ties -> class 0
    int tv = target[pix];
    if (tv == 255) tv = tmin;
    bool gt = (tv > 0);

    __shared__ unsigned long long mPC[4], mGT[4];
    unsigned long long bp = __ballot(pc);
    unsigned long long bg = __ballot(gt);
    if ((i & 63) == 0) { mPC[i >> 6] = bp; mGT[i >> 6] = bg; }
    __syncthreads();

    unsigned long long wp[4], wg[4], np[4], ng[4];
#pragma unroll
    for (int k = 0; k < 4; ++k) {
        wp[k] = mPC[k]; wg[k] = mGT[k];
        np[k] = ~wp[k]; ng[k] = ~wg[k];
    }

    pc_m2[pix]  = g2_of(wp, i, pc);
    pc_nm2[pix] = g2_of(np, i, !pc);
    gt_m2[pix]  = g2_of(wg, i, gt);
    gt_nm2[pix] = g2_of(ng, i, !gt);
}

// ---------------------------------------------------------------------------
// K2: fused horizontal pass for BOTH pc and gt + final elementwise math +
// per-block partial sum. One block per (b,i) row, thread j = column.
// Horizontal min uses exact early-exit outward search:
// once d*d >= mn for all lanes of a wave, no further k can improve.
__global__ void k_horiz_final(const float* __restrict__ preds,
                              const int*   __restrict__ target,
                              const int*   __restrict__ tminp,
                              const float* __restrict__ pc_m2,
                              const float* __restrict__ pc_nm2,
                              const float* __restrict__ gt_m2,
                              const float* __restrict__ gt_nm2,
                              float* __restrict__ partials) {
    const int row = blockIdx.x;            // 0 .. B*H-1
    const int b = row >> 8, i = row & 255;
    const int j = threadIdx.x;
    const size_t base = (size_t)row * WW;

    __shared__ float s_pm[WW], s_pn[WW], s_gm[WW], s_gn[WW];
    s_pm[j] = pc_m2[base + j];
    s_pn[j] = pc_nm2[base + j];
    s_gm[j] = gt_m2[base + j];
    s_gn[j] = gt_nm2[base + j];
    __syncthreads();

    float a0 = preds[((size_t)b * CC + 0) * HH * WW + (size_t)i * WW + j];
    float a1 = preds[((size_t)b * CC + 1) * HH * WW + (size_t)i * WW + j];
    bool pc = (a1 > a0);
    float pcv = pc ? 1.0f : 0.0f;

    int tv = target[base + j];
    if (tv == 255) tv = *tminp;
    float gtv = (float)tv;
    bool gt = (gtv > 0.0f);

    // --- pc distance (select the field that is nonzero at this pixel) ---
    const float* rv = pc ? s_pm : s_pn;
    float mn = rv[j];
    for (int d = 1; d < WW; ++d) {
        float dd = (float)(d * d);
        if (__all(dd >= mn)) break;
        int kl = j - d, kr = j + d;
        if (kl >= 0) mn = fminf(mn, dd + rv[kl]);
        if (kr < WW) mn = fminf(mn, dd + rv[kr]);
    }
    float pd = sqrtf(mn);

    // --- gt distance ---
    const float* rw = gt ? s_gm : s_gn;
    float mg = rw[j];
    for (int d = 1; d < WW; ++d) {
        float dd = (float)(d * d);
        if (__all(dd >= mg)) break;
        int kl = j - d, kr = j + d;
        if (kl >= 0) mg = fminf(mg, dd + rw[kl]);
        if (kr < WW) mg = fminf(mg, dd + rw[kr]);
    }
    float gd = sqrtf(mg);

    // --- final elementwise math (mirrors reference op order) ---
    float err  = fabsf(gtv - pcv);
    float dist = sqrtf(pd * pd + gd * gd);
    float mult = sqrtf(err * dist + 1e-9f);

    __shared__ float red[WW];
    red[j] = mult;
    __syncthreads();
    for (int st = 128; st > 0; st >>= 1) {
        if (j < st) red[j] += red[j + st];
        __syncthreads();
    }
    if (j == 0) partials[row] = red[0];
}

// ---------------------------------------------------------------------------
// K3: final deterministic reduction of B*H partials -> mean
__global__ void k_final(const float* __restrict__ partials, float* __restrict__ out) {
    __shared__ float s[256];
    float acc = 0.0f;
    for (int k = threadIdx.x; k < BB * HH; k += 256) acc += partials[k];
    s[threadIdx.x] = acc;
    __syncthreads();
    for (int st = 128; st > 0; st >>= 1) {
        if (threadIdx.x < st) s[threadIdx.x] += s[threadIdx.x + st];
        __syncthreads();
    }
    if (threadIdx.x == 0) out[0] = s[0] * (1.0f / (float)NPIX);  // /2^19: exact
}

// ---------------------------------------------------------------------------
extern "C" void kernel_launch(void* const* d_in, const int* in_sizes, int n_in,
                              void* d_out, int out_size, void* d_ws, size_t ws_size,
                              hipStream_t stream) {
    const float* preds  = (const float*)d_in[0];
    const int*   target = (const int*)d_in[1];
    float* out = (float*)d_out;

    const size_t N = (size_t)NPIX;
    float* ws       = (float*)d_ws;
    float* pc_m2    = ws;
    float* pc_nm2   = ws + 1 * N;
    float* gt_m2    = ws + 2 * N;
    float* gt_nm2   = ws + 3 * N;
    float* partials = ws + 4 * N;              // B*H = 2048 floats
    int*   tmin     = (int*)(ws + 4 * N + 2048);

    k_tmin_init<<<1, 1, 0, stream>>>(tmin);
    k_tmin<<<256, 256, 0, stream>>>(target, NPIX, tmin);
    k_vertical<<<BB * WW, HH, 0, stream>>>(
        preds, target, tmin, pc_m2, pc_nm2, gt_m2, gt_nm2);
    k_horiz_final<<<BB * HH, WW, 0, stream>>>(
        preds, target, tmin, pc_m2, pc_nm2, gt_m2, gt_nm2, partials);
    k_final<<<1, 256, 0, stream>>>(partials, out);
}